// Round 5
// baseline (823.262 us; speedup 1.0000x reference)
//
#include <hip/hip_runtime.h>

#define WS7    7
#define SHIFT3 3
#define NHEAD  6
#define CCH    192
#define HDIM   32
#define HH56   56
#define LTOK   (HH56*HH56)      // 3136
#define NWIN   64
#define NBATCH 32
#define NWTOT  (NBATCH*NWIN)    // 2048
#define LW     49
#define MTOK   (NWTOT*LW)       // 100352

typedef unsigned short u16;
typedef unsigned int   u32;
typedef __bf16 b16;
typedef b16   b16x8 __attribute__((ext_vector_type(8)));
typedef u16   u16x8 __attribute__((ext_vector_type(8)));
typedef float f32x4 __attribute__((ext_vector_type(4)));

__device__ __forceinline__ float b2f(u16 u) {
    u32 x = ((u32)u) << 16;
    return __builtin_bit_cast(float, x);
}
__device__ __forceinline__ u16 f2b(float f) {
    u32 x = __builtin_bit_cast(u32, f);
    u32 r = x + 0x7FFFu + ((x >> 16) & 1u);
    return (u16)(r >> 16);
}
// tanh-form gelu in sigmoid shape: x*sigmoid(1.59577*(x+0.044715x^3)); |err|<1.1e-3
__device__ __forceinline__ float gelu_fast(float x) {
    float u = x * fmaf(0.044715f * x, x, 1.0f);
    float e = __expf(-1.5957691216057308f * u);
    return x * __builtin_amdgcn_rcpf(1.0f + e);
}

// async global->LDS, 16B per lane (dest = wave-uniform base + lane*16)
__device__ __forceinline__ void glds16(const u16* g, void* lds) {
    __builtin_amdgcn_global_load_lds(
        (const __attribute__((address_space(1))) unsigned int*)(unsigned long long)(const void*)g,
        (__attribute__((address_space(3))) unsigned int*)(unsigned int)(unsigned long long)lds,
        16, 0, 0);
}

// token m (window-order) -> (b, l) image order (bijection)
__device__ __forceinline__ int map_token(int m, int &b) {
    int widx = m / LW, p = m - widx * LW;
    b = widx >> 6;
    int wloc = widx & 63;
    int wh = wloc >> 3, ww = wloc & 7;
    int i = p / WS7, j = p - i * WS7;
    int gh = wh * WS7 + i + SHIFT3; if (gh >= HH56) gh -= HH56;
    int gw = ww * WS7 + j + SHIFT3; if (gw >= HH56) gw -= HH56;
    return gh * HH56 + gw;
}

// ---- dtype probe (4096 u16): fp32 storage -> ~512 high-exp or ~2048 zero u16s
__global__ __launch_bounds__(256) void probe_kernel(const u16* __restrict__ x, int* flag) {
    __shared__ int ch, cz;
    if (threadIdx.x == 0) { ch = 0; cz = 0; }
    __syncthreads();
    int h = 0, z = 0;
    for (int i = threadIdx.x; i < 4096; i += 256) {
        u16 u = x[i];
        int e = (u >> 7) & 0xFF;
        h += (e >= 0xC0);
        z += (u == 0);
    }
    atomicAdd(&ch, h);
    atomicAdd(&cz, z);
    __syncthreads();
    if (threadIdx.x == 0) *flag = (ch > 64 || cz > 512) ? 1 : 0;
}

// ---- all params -> bf16 arena in one launch
struct CanonSrc { const void* p[12]; };
#define CANON_TOT 445302
__global__ __launch_bounds__(256) void canon_all_kernel(const int* __restrict__ flag,
                                                        CanonSrc srcs, u16* __restrict__ dst) {
    int g = blockIdx.x * 256 + threadIdx.x;
    if (g >= CANON_TOT) return;
    const int start[13] = {0, 110592, 147456, 294912, 442368, 442560, 442752,
                           442944, 443136, 443328, 444096, 444288, CANON_TOT};
    int s = 0;
    #pragma unroll
    for (int i = 1; i < 12; i++) s += (g >= start[i]);
    int off = g - start[s];
    if (*flag) dst[g] = f2b(((const float*)srcs.p[s])[off]);
    else       dst[g] = ((const u16*)srcs.p[s])[off];
}

// ---- LayerNorm. GATHER=1: src = d_in[0] (dtype per flag), rows via map_token.
template<int GATHER>
__global__ __launch_bounds__(256) void ln_kernel(
    const void* __restrict__ src, const u16* __restrict__ w, const u16* __restrict__ bia,
    u16* __restrict__ dst, int m_base, const int* __restrict__ flag)
{
    int wave = threadIdx.x >> 6, lane = threadIdx.x & 63;
    int mloc = blockIdx.x * 4 + wave;
    size_t row;
    if (GATHER) { int b; int l = map_token(m_base + mloc, b); row = (size_t)b * LTOK + l; }
    else row = mloc;
    float v0, v1, v2;
    if (GATHER && *flag) {
        const float* xp = (const float*)src + row * CCH;
        v0 = xp[lane]; v1 = xp[lane + 64]; v2 = xp[lane + 128];
    } else {
        const u16* xp = (const u16*)src + row * CCH;
        v0 = b2f(xp[lane]); v1 = b2f(xp[lane + 64]); v2 = b2f(xp[lane + 128]);
    }
    float s = v0 + v1 + v2, sq = v0 * v0 + v1 * v1 + v2 * v2;
    for (int off = 32; off > 0; off >>= 1) {
        s  += __shfl_xor(s, off, 64);
        sq += __shfl_xor(sq, off, 64);
    }
    float mean = s * (1.f / 192.f);
    float var  = fmaxf(sq * (1.f / 192.f) - mean * mean, 0.f);
    float rstd = rsqrtf(var + 1e-5f);
    u16* op = dst + (size_t)mloc * CCH;
    op[lane]       = f2b((v0 - mean) * rstd * b2f(w[lane])       + b2f(bia[lane]));
    op[lane + 64]  = f2b((v1 - mean) * rstd * b2f(w[lane + 64])  + b2f(bia[lane + 64]));
    op[lane + 128] = f2b((v2 - mean) * rstd * b2f(w[lane + 128]) + b2f(bia[lane + 128]));
}

// ---- GEMM: D[m][n] = sum_k A[m][k]*Bm[n][k]. 256x64 tile, BK=32, glds staging.
// wave owns 64 rows x 64 cols (4x4 subtiles of 16x16), 16 MFMA + 8 ds_read_b128 / K-step.
// MODE 0: store bf16. MODE 1: +bias, scatter via map_token, X1 = Xin(flag)+val.
// MODE 2: +bias, gelu -> bf16. MODE 3: +bias, gelu, +X1 -> Oout (flag dtype) at o_off.
template<int MODE>
__global__ __launch_bounds__(256) void gemm_bt_kernel(
    const u16* __restrict__ A, const u16* __restrict__ Bm, int K, int N,
    const u16* __restrict__ bias,
    u16* __restrict__ Cb,
    u16* __restrict__ X1,
    const void* __restrict__ Xin,
    void* __restrict__ Oout, size_t o_off, int m_base,
    const int* __restrict__ flag)
{
    __shared__ __align__(16) u16 As[256 * 32];
    __shared__ __align__(16) u16 Bs[64 * 32];
    int isf = (MODE == 1 || MODE == 3) ? *flag : 0;
    int tid = threadIdx.x;
    int m0 = blockIdx.x * 256, n0 = blockIdx.y * 64;
    int wave = tid >> 6, lane = tid & 63;
    int quad = lane >> 4, cc = lane & 15;

    f32x4 acc[4][4] = {};

    int lrow = tid >> 2, lcol = (tid & 3) * 8;
    const u16* gA = A  + (size_t)(m0 + lrow) * K + lcol;
    const u16* gB = Bm + (size_t)(n0 + lrow) * K + lcol;
    char* aDst = (char*)As + tid * 16;
    char* bDst = (char*)Bs + tid * 16;
    const u16* pa = &As[(wave * 64 + cc) * 32 + quad * 8];
    const u16* pb = &Bs[cc * 32 + quad * 8];

    for (int k0 = 0; k0 < K; k0 += 32) {
        #pragma unroll
        for (int i = 0; i < 4; i++)
            glds16(gA + (size_t)(i * 64) * K + k0, aDst + i * 4096);
        glds16(gB + k0, bDst);
        __syncthreads();
        b16x8 af[4], bf[4];
        #pragma unroll
        for (int s = 0; s < 4; s++) {
            af[s] = __builtin_bit_cast(b16x8, *(const u16x8*)(pa + s * 16 * 32));
            bf[s] = __builtin_bit_cast(b16x8, *(const u16x8*)(pb + s * 16 * 32));
        }
        #pragma unroll
        for (int sm = 0; sm < 4; sm++)
            #pragma unroll
            for (int sn = 0; sn < 4; sn++)
                acc[sm][sn] = __builtin_amdgcn_mfma_f32_16x16x32_bf16(af[sm], bf[sn], acc[sm][sn], 0, 0, 0);
        __syncthreads();
    }

    #pragma unroll
    for (int sm = 0; sm < 4; sm++) {
        #pragma unroll
        for (int r = 0; r < 4; r++) {
            int mm = m0 + wave * 64 + sm * 16 + quad * 4 + r;
            size_t rowidx = 0;
            if (MODE == 1) {
                int b; int l = map_token(m_base + mm, b);
                rowidx = ((size_t)b * LTOK + l) * CCH;
            }
            #pragma unroll
            for (int sn = 0; sn < 4; sn++) {
                int nn = n0 + sn * 16 + cc;
                float val = acc[sm][sn][r];
                if (MODE == 0) {
                    Cb[(size_t)mm * N + nn] = f2b(val);
                } else if (MODE == 1) {
                    val += b2f(bias[nn]);
                    size_t idx = rowidx + nn;
                    float xi = isf ? ((const float*)Xin)[idx] : b2f(((const u16*)Xin)[idx]);
                    X1[idx] = f2b(xi + val);
                } else if (MODE == 2) {
                    val = gelu_fast(val + b2f(bias[nn]));
                    Cb[(size_t)mm * N + nn] = f2b(val);
                } else {
                    val = gelu_fast(val + b2f(bias[nn]));
                    size_t idx = (size_t)mm * CCH + nn;
                    float r2 = val + b2f(X1[idx]);
                    if (isf) ((float*)Oout)[o_off + idx] = r2;
                    else     ((u16*)Oout)[o_off + idx]  = f2b(r2);
                }
            }
        }
    }
}

// ---- MFMA attention: 1 block = 1 (window, head); 4 waves = 4 row-tiles of 64x64 S.
__global__ __launch_bounds__(256) void attn_kernel(
    const u16* __restrict__ qkv, const u16* __restrict__ rel_bias,
    u16* __restrict__ aout)
{
    __shared__ __align__(16) u16 qs[64 * 32];
    __shared__ __align__(16) u16 ks[64 * 32];
    __shared__ __align__(16) u16 vsT[32 * 64];
    __shared__ __align__(16) u16 ps[64 * 64];
    __shared__ float bias_s[169];
    int blk = blockIdx.x;
    int widx = blk / NHEAD, head = blk - widx * NHEAD;
    int wloc = widx & 63;
    int wh = wloc >> 3, ww = wloc & 7;
    int tid = threadIdx.x;
    const u16* base = qkv + (size_t)widx * LW * 576 + head * HDIM;

    if (tid < 196) {
        int i = tid >> 2, c = (tid & 3) * 8;
        *(uint4*)&qs[i * 32 + c] = *(const uint4*)(base + (size_t)i * 576 + c);
        *(uint4*)&ks[i * 32 + c] = *(const uint4*)(base + (size_t)i * 576 + 192 + c);
    }
    for (int idx = tid; idx < 32 * 64; idx += 256) {
        int d = idx >> 6, j = idx & 63;
        vsT[d * 64 + j] = (j < LW) ? base[(size_t)j * 576 + 384 + d] : (u16)0;
    }
    if (tid < 169) bias_s[tid] = b2f(rel_bias[tid * NHEAD + head]);
    __syncthreads();

    int wave = tid >> 6, lane = tid & 63;
    int quad = lane >> 4, c = lane & 15;

    b16x8 aq = __builtin_bit_cast(b16x8, *(const u16x8*)&qs[(wave * 16 + c) * 32 + quad * 8]);
    f32x4 sacc[4];
    #pragma unroll
    for (int nt = 0; nt < 4; nt++) {
        b16x8 bk = __builtin_bit_cast(b16x8, *(const u16x8*)&ks[(nt * 16 + c) * 32 + quad * 8]);
        f32x4 z = {};
        sacc[nt] = __builtin_amdgcn_mfma_f32_16x16x32_bf16(aq, bk, z, 0, 0, 0);
    }

    const float SCALE = 13.856406460551018f;
    float val[4][4];
    int rbase = wave * 16 + quad * 4;
    #pragma unroll
    for (int r = 0; r < 4; r++) {
        int i = rbase + r;
        int ih = i / WS7, iw = i - ih * WS7;
        int ri = (wh == 7 ? (ih < 4 ? 1 : 2) : 0) * 3 + (ww == 7 ? (iw < 4 ? 1 : 2) : 0);
        #pragma unroll
        for (int nt = 0; nt < 4; nt++) {
            int j = nt * 16 + c;
            float v;
            if (i >= LW) v = 0.f;
            else if (j >= LW) v = -1e30f;
            else {
                int jh = j / WS7, jw = j - jh * WS7;
                int rj = (wh == 7 ? (jh < 4 ? 1 : 2) : 0) * 3 + (ww == 7 ? (jw < 4 ? 1 : 2) : 0);
                if (ri != rj) v = -100.0f;
                else v = fmaf(sacc[nt][r], SCALE, bias_s[(ih - jh + 6) * 13 + (iw - jw + 6)]);
            }
            val[r][nt] = v;
        }
    }

    #pragma unroll
    for (int r = 0; r < 4; r++) {
        float mx = fmaxf(fmaxf(val[r][0], val[r][1]), fmaxf(val[r][2], val[r][3]));
        for (int d = 1; d < 16; d <<= 1) mx = fmaxf(mx, __shfl_xor(mx, d, 64));
        float sum = 0.f;
        #pragma unroll
        for (int nt = 0; nt < 4; nt++) { float e = expf(val[r][nt] - mx); val[r][nt] = e; sum += e; }
        for (int d = 1; d < 16; d <<= 1) sum += __shfl_xor(sum, d, 64);
        float inv = 1.f / sum;
        int i = rbase + r;
        #pragma unroll
        for (int nt = 0; nt < 4; nt++)
            ps[i * 64 + nt * 16 + c] = f2b(val[r][nt] * inv);
    }

    f32x4 oacc[2] = {{}, {}};
    #pragma unroll
    for (int kh = 0; kh < 2; kh++) {
        b16x8 ap = __builtin_bit_cast(b16x8, *(const u16x8*)&ps[(wave * 16 + c) * 64 + kh * 32 + quad * 8]);
        #pragma unroll
        for (int nt = 0; nt < 2; nt++) {
            b16x8 bv = __builtin_bit_cast(b16x8, *(const u16x8*)&vsT[(nt * 16 + c) * 64 + kh * 32 + quad * 8]);
            oacc[nt] = __builtin_amdgcn_mfma_f32_16x16x32_bf16(ap, bv, oacc[nt], 0, 0, 0);
        }
    }
    #pragma unroll
    for (int nt = 0; nt < 2; nt++) {
        #pragma unroll
        for (int r = 0; r < 4; r++) {
            int i = rbase + r;
            if (i < LW)
                aout[((size_t)widx * LW + i) * CCH + head * HDIM + nt * 16 + c] = f2b(oacc[nt][r]);
        }
    }
}

extern "C" void kernel_launch(void* const* d_in, const int* in_sizes, int n_in,
                              void* d_out, int out_size, void* d_ws, size_t ws_size,
                              hipStream_t stream)
{
    const void* x_in = d_in[0];
    char* ws = (char*)d_ws;
    int* flag = (int*)ws;

    u16* parr = (u16*)(ws + 64);
    u16* qkvw_c  = parr;
    u16* projw_c = parr + 110592;
    u16* fc1w_c  = parr + 147456;
    u16* fc2w_c  = parr + 294912;
    u16* n1w_c   = parr + 442368;
    u16* n1b_c   = parr + 442560;
    u16* n2w_c   = parr + 442752;
    u16* n2b_c   = parr + 442944;
    u16* projb_c = parr + 443136;
    u16* fc1b_c  = parr + 443328;
    u16* fc2b_c  = parr + 444096;
    u16* relb_c  = parr + 444288;

    const size_t P0 = 1u << 20;
    u16* x1   = (u16*)(ws + P0);                         // 38,535,168 B
    u16* winq = (u16*)(ws + P0 + 38535168);              //  9,633,792 B (stage A)
    u16* qkvq = (u16*)(ws + P0 + 38535168 + 9633792);    // 28,901,376 B (stage A)
    u16* xnq  = winq;                                    //  9,633,792 B (stage B)
    u16* h1q  = (u16*)(ws + P0 + 38535168 + 9633792);    // 38,535,168 B (stage B; peak ~87.7 MB)

    probe_kernel<<<1, 256, 0, stream>>>((const u16*)x_in, flag);
    CanonSrc cs = {{d_in[7], d_in[9], d_in[13], d_in[15], d_in[5], d_in[6],
                    d_in[11], d_in[12], d_in[10], d_in[14], d_in[16], d_in[8]}};
    canon_all_kernel<<<(CANON_TOT + 255) / 256, 256, 0, stream>>>(flag, cs, parr);

    const int M4 = MTOK / 4;   // 25088 = 98 * 256

    for (int q = 0; q < 4; q++) {
        int mb = q * M4;
        ln_kernel<1><<<M4 / 4, 256, 0, stream>>>(x_in, n1w_c, n1b_c, winq, mb, flag);
        gemm_bt_kernel<0><<<dim3(M4 / 256, 9), 256, 0, stream>>>(
            winq, qkvw_c, 192, 576, nullptr, qkvq, nullptr, nullptr, nullptr, 0, 0, flag);
        attn_kernel<<<(NWTOT / 4) * NHEAD, 256, 0, stream>>>(qkvq, relb_c, winq);
        gemm_bt_kernel<1><<<dim3(M4 / 256, 3), 256, 0, stream>>>(
            winq, projw_c, 192, 192, projb_c, nullptr, x1, x_in, nullptr, 0, mb, flag);
    }

    for (int q = 0; q < 4; q++) {
        size_t off = (size_t)q * M4 * CCH;
        ln_kernel<0><<<M4 / 4, 256, 0, stream>>>(x1 + off, n2w_c, n2b_c, xnq, 0, flag);
        gemm_bt_kernel<2><<<dim3(M4 / 256, 12), 256, 0, stream>>>(
            xnq, fc1w_c, 192, 768, fc1b_c, h1q, nullptr, nullptr, nullptr, 0, 0, flag);
        gemm_bt_kernel<3><<<dim3(M4 / 256, 3), 256, 0, stream>>>(
            h1q, fc2w_c, 768, 192, fc2b_c, nullptr, x1 + off, nullptr, d_out, off, 0, flag);
    }
}